// Round 6
// baseline (301.740 us; speedup 1.0000x reference)
//
#include <hip/hip_runtime.h>
#include <math.h>

namespace {

constexpr int Bb   = 128;
constexpr int Ss   = 196;
constexpr int DIN  = 512;
constexpr int Hh   = 8;
constexpr int DKc  = 32;
constexpr int DVc  = 128;
constexpr int QKVD = 1536;   // H*(2*DK+DV)
constexpr int PIN  = 1024;   // H*DV
constexpr int Mrows = Bb * Ss; // 25088
constexpr float EPSc   = 1e-3f;
constexpr float SCALEc = 0.17677669529663687f; // 32^-0.5

typedef __bf16 bf16x8 __attribute__((ext_vector_type(8)));
typedef __bf16 bf16x4 __attribute__((ext_vector_type(4)));
typedef float  f32x4  __attribute__((ext_vector_type(4)));

// VT layout: [bh][quarter(4)][ 8192 elems ], quarter row stride 232 elems.
constexpr int VT_STRIDE = 232;                 // elems; 464 B = 16B-aligned, 2-way banks
constexpr size_t VT_QELEMS = 8192;             // padded quarter (32 rows x 232 = 7424 used)
constexpr size_t VT_BH = 4 * VT_QELEMS;        // 32768 elems per (b,h)

__device__ __forceinline__ void gl_lds16(const void* g, void* l) {
    __builtin_amdgcn_global_load_lds(
        (const __attribute__((address_space(1))) void*)g,
        (__attribute__((address_space(3))) void*)l, 16, 0, 0);
}

// ---------------- W[K][N] fp32 -> WT[N][K] bf16 (both weights, one launch) ----------------
// blocks [0,768): Wqkv (K=512,N=1536) as (48 x 16); [768,1280): Wproj (K=1024,N=512) as (16 x 32)
__global__ __launch_bounds__(256)
void transpose_cvt2(const float* __restrict__ W1, __bf16* __restrict__ WT1o,
                    const float* __restrict__ W2, __bf16* __restrict__ WT2o)
{
    __shared__ float tile[32][33];
    int id = blockIdx.x;
    const float* W; __bf16* WT; int K, N, bx, by;
    if (id < 768) { W = W1; WT = WT1o; K = 512;  N = 1536; bx = id % 48; by = id / 48; }
    else { id -= 768; W = W2; WT = WT2o; K = 1024; N = 512;  bx = id % 16; by = id / 16; }
    const int n0 = bx * 32, k0 = by * 32;
    const int tx = threadIdx.x & 31, ty = threadIdx.x >> 5;
#pragma unroll
    for (int i = ty; i < 32; i += 8)
        tile[i][tx] = W[(size_t)(k0 + i) * N + n0 + tx];
    __syncthreads();
#pragma unroll
    for (int i = ty; i < 32; i += 8)
        WT[(size_t)(n0 + i) * K + k0 + tx] = (__bf16)tile[tx][i];
}

// ---------------- GEMM1: x(f32)@Wqkv + BN, LDS-shuffle epilogue ----------------
// v6: A-staging fused with f32->bf16 conversion (reg-staged, T14 split:
// issue float4 loads of tile t+1 BEFORE the MFMA phase, cvt+ds_write AFTER it).
// B stays global_load_lds. LDS layout/fragments/epilogue identical to v5.
// Eliminates the standalone cvt kernel (77 MB HBM traffic + a launch).
__global__ __launch_bounds__(256)
void gemm1_bn_scatter(const float* __restrict__ X, const __bf16* __restrict__ BT,
                      const float* __restrict__ bias, const float* __restrict__ gamma,
                      const float* __restrict__ beta, const float* __restrict__ mean,
                      const float* __restrict__ var,
                      __bf16* __restrict__ qkvO, __bf16* __restrict__ VTp)
{
    constexpr int N = QKVD, K = DIN;
    constexpr int BM = 128, BN = 128;
    __shared__ __align__(16) char sm[65536];

    const int t    = threadIdx.x;
    const int wave = t >> 6;
    const int lane = t & 63;
    const int lr   = lane & 15;
    const int q    = lane >> 4;

    constexpr int ntiles = N / BN;           // 12
    // T1: bijective XCD swizzle (nwg = 2352, divisible by 8).
    constexpr int nwg = 196 * ntiles;
    const int bid = (blockIdx.x & 7) * (nwg >> 3) + (blockIdx.x >> 3);
    const int m0 = (bid / ntiles) * BM;
    const int n0 = (bid % ntiles) * BN;
    const int wm = (wave & 1) * 64;
    const int wn = (wave >> 1) * 64;

    const float*  xA  = X  + (size_t)(m0 + (t >> 2)) * K + (t & 3) * 8;
    const __bf16* bG0 = BT + (size_t)(n0 + (t >> 2)) * K + (t & 3) * 8;
    const __bf16* bG1 = bG0 + (size_t)64 * K;

    // A: 4 chunks/thread: {kk0,kk1} x {rows 0-63, rows 64-127}; each = 8 f32 = 2 float4
    float4 fa[4][2];
    auto LOADA = [&](int k0) {
        const float* p = xA + k0;
        fa[0][0] = *(const float4*)(p);
        fa[0][1] = *(const float4*)(p + 4);
        fa[1][0] = *(const float4*)(p + 64 * K);
        fa[1][1] = *(const float4*)(p + 64 * K + 4);
        fa[2][0] = *(const float4*)(p + 32);
        fa[2][1] = *(const float4*)(p + 36);
        fa[3][0] = *(const float4*)(p + 64 * K + 32);
        fa[3][1] = *(const float4*)(p + 64 * K + 36);
    };
    // LDS dest byte offset = c*4096 + t*16  (same linear layout gl_lds produced in v5)
    auto WRITEA = [&](int cur) {
        char* base = sm + cur * 16384;
#pragma unroll
        for (int c = 0; c < 4; ++c) {
            bf16x8 w = { (__bf16)fa[c][0].x, (__bf16)fa[c][0].y,
                         (__bf16)fa[c][0].z, (__bf16)fa[c][0].w,
                         (__bf16)fa[c][1].x, (__bf16)fa[c][1].y,
                         (__bf16)fa[c][1].z, (__bf16)fa[c][1].w };
            *(bf16x8*)(base + c * 4096 + t * 16) = w;
        }
    };
    auto STAGEB = [&](int k0, int cur) {
        char* lB = sm + 32768 + cur * 16384 + wave * 1024;
        gl_lds16(bG0 + k0,      lB);
        gl_lds16(bG1 + k0,      lB + 4096);
        gl_lds16(bG0 + k0 + 32, lB + 8192);
        gl_lds16(bG1 + k0 + 32, lB + 8192 + 4096);
    };

    f32x4 acc[4][4] = {};

    LOADA(0); STAGEB(0, 0); WRITEA(0);
    __syncthreads();                 // buf0 ready (vmcnt+lgkm drained)
    int cur = 0;
    for (int k0 = 0; k0 < K; k0 += 64) {
        const bool next = (k0 + 64 < K);
        if (next) { LOADA(k0 + 64); STAGEB(k0 + 64, cur ^ 1); }   // issue early
        const __bf16* Abuf = (const __bf16*)(sm + cur * 16384);
        const __bf16* Bbuf = (const __bf16*)(sm + 32768 + cur * 16384);
#pragma unroll
        for (int kk = 0; kk < 2; ++kk) {
            bf16x8 aF[4], bF[4];
#pragma unroll
            for (int i = 0; i < 4; ++i)
                aF[i] = *(const bf16x8*)(Abuf + kk * 4096 + (wm + i * 16 + lr) * 32 + q * 8);
#pragma unroll
            for (int j = 0; j < 4; ++j)
                bF[j] = *(const bf16x8*)(Bbuf + kk * 4096 + (wn + j * 16 + lr) * 32 + q * 8);
#pragma unroll
            for (int i = 0; i < 4; ++i)
#pragma unroll
                for (int j = 0; j < 4; ++j)
                    acc[i][j] = __builtin_amdgcn_mfma_f32_16x16x32_bf16(
                        aF[i], bF[j], acc[i][j], 0, 0, 0);
        }
        if (next) WRITEA(cur ^ 1);   // cvt + ds_write late: loads landed under MFMA
        __syncthreads();             // reads of buf[cur] done + next tile fully landed
        cur ^= 1;
    }

    // ---- epilogue: BN + stage to LDS overlay (over the dbuf space) ----
    const int tmod = n0 % 384;
    const int cq0  = (tmod == 0) ? 0 : (tmod == 128 ? 64 : -1);
    const int vc0  = (tmod == 0) ? 64 : 0;
    const int nv   = (tmod == 256) ? 128 : 64;
    const bool qk_wave = (tmod == 0) ? (wn == 0) : (tmod == 128 ? (wn == 64) : false);

    __bf16* qkreg = (__bf16*)sm;                                   // [128][72]
    __bf16* vreg  = (__bf16*)(sm + ((nv == 128) ? 0 : 18432));     // [nv][136] col-major
    const int vbase = (nv == 128) ? wn : 0;

#pragma unroll
    for (int j = 0; j < 4; ++j) {
        const int n = n0 + wn + j * 16 + lr;
        const float s  = gamma[n] * rsqrtf(var[n] + EPSc);
        const float tv = fmaf(bias[n] - mean[n], s, beta[n]);
        if (qk_wave) {
#pragma unroll
            for (int i = 0; i < 4; ++i) {
                const int row = wm + i * 16 + q * 4;
#pragma unroll
                for (int r = 0; r < 4; ++r)
                    qkreg[(row + r) * 72 + j * 16 + lr] = (__bf16)fmaf(acc[i][j][r], s, tv);
            }
        } else {
#pragma unroll
            for (int i = 0; i < 4; ++i) {
                bf16x4 pk = { (__bf16)fmaf(acc[i][j][0], s, tv),
                              (__bf16)fmaf(acc[i][j][1], s, tv),
                              (__bf16)fmaf(acc[i][j][2], s, tv),
                              (__bf16)fmaf(acc[i][j][3], s, tv) };
                *(bf16x4*)(vreg + (vbase + j * 16 + lr) * 136 + wm + i * 16 + q * 4) = pk;
            }
        }
    }
    __syncthreads();

    // ---- QK write-out: full 128 B lines (8 lanes x 16 B) ----
    if (cq0 >= 0) {
#pragma unroll
        for (int rr = 0; rr < 4; ++rr) {
            const int row = rr * 32 + (t >> 3);
            const int l   = t & 7;
            bf16x8 vv = *(const bf16x8*)(qkreg + row * 72 + l * 8);
            *(bf16x8*)(qkvO + (size_t)(m0 + row) * N + n0 + cq0 + l * 8) = vv;
        }
    }
    // ---- V write-out: 16 B along s into VTp ----
    const int iters = (nv * 16) / 256;   // 4 or 8
    for (int it = 0; it < iters; ++it) {
        const int a  = it * 256 + t;
        const int cl = a >> 4;           // local V col
        const int r0 = (a & 15) * 8;     // tile row of first elem
        const int n  = n0 + vc0 + cl;
        const int h  = n / 192;
        const int d  = n - h * 192 - 64;
        const int mr = m0 + r0;
        const int b_ = mr / 196;
        const int s0 = mr - b_ * 196;
        __bf16* dst0 = VTp + (size_t)(b_ * 8 + h) * VT_BH
                     + (size_t)(d >> 5) * VT_QELEMS + (size_t)(d & 31) * VT_STRIDE;
        bf16x8 vv = *(const bf16x8*)(vreg + cl * 136 + r0);
        if (s0 <= 188) {
            *(bf16x8*)(dst0 + s0) = vv;
        } else {
            // chunk straddles a batch boundary (s wraps at 196): scalar split
#pragma unroll
            for (int e = 0; e < 8; ++e) {
                int se = s0 + e;
                __bf16* dst = dst0;
                if (se >= 196) { se -= 196; dst += 8 * VT_BH; }
                dst[se] = vv[e];
            }
        }
    }
}

// ---------------- generic bf16 MFMA GEMM + BN (fp32 out) — GEMM2 ----------------
// v5 structure: double-buffered single-barrier K-loop.
template<int N, int K>
__global__ __launch_bounds__(256)
void gemm_bn_mfma(const __bf16* __restrict__ A, const __bf16* __restrict__ BT,
                  const float* __restrict__ bias, const float* __restrict__ gamma,
                  const float* __restrict__ beta, const float* __restrict__ mean,
                  const float* __restrict__ var, float* __restrict__ C)
{
    constexpr int BM = 128, BN = 128;
    __shared__ __align__(16) char sm[65536];
    const int t    = threadIdx.x;
    const int wave = t >> 6;
    const int lane = t & 63;
    const int lr   = lane & 15;
    const int q    = lane >> 4;
    constexpr int ntiles = N / BN;
    constexpr int nwg = 196 * ntiles;        // 784 for N=512 -> divisible by 8
    const int bid = (blockIdx.x & 7) * (nwg >> 3) + (blockIdx.x >> 3);
    const int m0 = (bid / ntiles) * BM;
    const int n0 = (bid % ntiles) * BN;
    const int wm = (wave & 1) * 64;
    const int wn = (wave >> 1) * 64;
    const __bf16* aG0 = A  + (size_t)(m0 + (t >> 2)) * K + (t & 3) * 8;
    const __bf16* aG1 = aG0 + (size_t)64 * K;
    const __bf16* bG0 = BT + (size_t)(n0 + (t >> 2)) * K + (t & 3) * 8;
    const __bf16* bG1 = bG0 + (size_t)64 * K;

    auto STAGE = [&](int k0, int cur) {
        char* lA = sm + cur * 16384 + wave * 1024;
        char* lB = sm + 32768 + cur * 16384 + wave * 1024;
        gl_lds16(aG0 + k0,      lA);
        gl_lds16(aG1 + k0,      lA + 4096);
        gl_lds16(aG0 + k0 + 32, lA + 8192);
        gl_lds16(aG1 + k0 + 32, lA + 8192 + 4096);
        gl_lds16(bG0 + k0,      lB);
        gl_lds16(bG1 + k0,      lB + 4096);
        gl_lds16(bG0 + k0 + 32, lB + 8192);
        gl_lds16(bG1 + k0 + 32, lB + 8192 + 4096);
    };

    f32x4 acc[4][4] = {};

    STAGE(0, 0);
    __syncthreads();
    int cur = 0;
    for (int k0 = 0; k0 < K; k0 += 64) {
        if (k0 + 64 < K) STAGE(k0 + 64, cur ^ 1);
        const __bf16* Abuf = (const __bf16*)(sm + cur * 16384);
        const __bf16* Bbuf = (const __bf16*)(sm + 32768 + cur * 16384);
#pragma unroll
        for (int kk = 0; kk < 2; ++kk) {
            bf16x8 aF[4], bF[4];
#pragma unroll
            for (int i = 0; i < 4; ++i)
                aF[i] = *(const bf16x8*)(Abuf + kk * 4096 + (wm + i * 16 + lr) * 32 + q * 8);
#pragma unroll
            for (int j = 0; j < 4; ++j)
                bF[j] = *(const bf16x8*)(Bbuf + kk * 4096 + (wn + j * 16 + lr) * 32 + q * 8);
#pragma unroll
            for (int i = 0; i < 4; ++i)
#pragma unroll
                for (int j = 0; j < 4; ++j)
                    acc[i][j] = __builtin_amdgcn_mfma_f32_16x16x32_bf16(
                        aF[i], bF[j], acc[i][j], 0, 0, 0);
        }
        __syncthreads();
        cur ^= 1;
    }
#pragma unroll
    for (int j = 0; j < 4; ++j) {
        const int n = n0 + wn + j * 16 + lr;
        const float s  = gamma[n] * rsqrtf(var[n] + EPSc);
        const float tv = fmaf(bias[n] - mean[n], s, beta[n]);
#pragma unroll
        for (int i = 0; i < 4; ++i) {
            const int mrow = m0 + wm + i * 16 + q * 4;
#pragma unroll
            for (int r = 0; r < 4; ++r)
                C[(size_t)(mrow + r) * N + n] = fmaf(acc[i][j][r], s, tv);
        }
    }
}

// ---------------- MFMA attention v2: one block per (b,h), 16 waves ----------------
// wave w owns q-tile qt = w (16 q-rows); 13 active tiles cover S=196 (pad to 208).
// K staged ONCE, V quarters streamed ONCE each (double-buffered, issue-early).
// LDS: Kb[208][40] (16640 B) | P: 13 x [16][232] (96512 B) | V dbuf 2x16384 = 145920 B
__global__ __launch_bounds__(1024)
void attn_mfma(const __bf16* __restrict__ qkv, const __bf16* __restrict__ VTp,
               __bf16* __restrict__ hidden)
{
    __shared__ __align__(16) char smem[145920];
    __bf16* Kb = (__bf16*)smem;

    const int t = threadIdx.x;
    const int wave = t >> 6, lane = t & 63;
    const int lr = lane & 15, q = lane >> 4;
    const int bh = blockIdx.x;
    const int b = bh >> 3, h = bh & 7;
    const __bf16* qkvb = qkv + (size_t)b * 196 * QKVD + h * 192;

    // ---- issue V quarter 0 stage FIRST so HBM latency drains under K staging ----
    const char* gV = (const char*)(VTp + (size_t)bh * VT_BH);
    char* ldsV = smem + 113152;                 // 2 x 16384 double buffer
    gl_lds16(gV + wave * 1024 + lane * 16, ldsV + wave * 1024);

    // ---- stage K once: rows s=0..195, ch 32..63 -> Kb[s][40] ----
    if (t < 196 * 4) {
        const int s = t >> 2, c = t & 3;
        bf16x8 v = *(const bf16x8*)(qkvb + (size_t)s * QKVD + 32 + c * 8);
        *(bf16x8*)(Kb + s * 40 + c * 8) = v;
    }

    __syncthreads();                            // K ready; barrier drains vmcnt -> V0 ready

    const int qt = wave;                        // q-tile; valid rows only for qt<=12
    const bool wactive = (qt <= 12);
    __bf16* Pw = (__bf16*)(smem + 16640 + (wactive ? qt : 0) * 7424);   // [16][232]

    if (wactive) {
        // Q fragment straight from global
        int sQ = qt * 16 + lr; if (sQ > 195) sQ = 195;
        bf16x8 aQ = *(const bf16x8*)(qkv + ((size_t)b * 196 + sQ) * QKVD + h * 192 + q * 8);

        f32x4 sc[13];
#pragma unroll
        for (int nt = 0; nt < 13; ++nt) {
            bf16x8 bK = *(const bf16x8*)(Kb + (nt * 16 + lr) * 40 + q * 8);
            f32x4 z = {0.f, 0.f, 0.f, 0.f};
            sc[nt] = __builtin_amdgcn_mfma_f32_16x16x32_bf16(aQ, bK, z, 0, 0, 0);
        }
        // ---- register softmax over the 208 cols (cols>=196 masked) ----
        float mrow[4] = {-1e30f, -1e30f, -1e30f, -1e30f};
#pragma unroll
        for (int nt = 0; nt < 13; ++nt) {
            const bool valid = (nt < 12) | (lr < 4);
#pragma unroll
            for (int r = 0; r < 4; ++r) {
                float x = sc[nt][r] * SCALEc;
                sc[nt][r] = x;
                if (valid) mrow[r] = fmaxf(mrow[r], x);
            }
        }
#pragma unroll
        for (int d = 1; d < 16; d <<= 1)
#pragma unroll
            for (int r = 0; r < 4; ++r)
                mrow[r] = fmaxf(mrow[r], __shfl_xor(mrow[r], d, 64));
        float l[4] = {0.f, 0.f, 0.f, 0.f};
#pragma unroll
        for (int nt = 0; nt < 13; ++nt) {
            const bool valid = (nt < 12) | (lr < 4);
#pragma unroll
            for (int r = 0; r < 4; ++r) {
                float e = valid ? __expf(sc[nt][r] - mrow[r]) : 0.f;
                sc[nt][r] = e;
                l[r] += e;
            }
        }
#pragma unroll
        for (int d = 1; d < 16; d <<= 1)
#pragma unroll
            for (int r = 0; r < 4; ++r)
                l[r] += __shfl_xor(l[r], d, 64);
        float inv[4];
#pragma unroll
        for (int r = 0; r < 4; ++r) inv[r] = 1.f / l[r];

        // ---- P to LDS in A-operand layout: P[m=quad*4+r][col] ----
#pragma unroll
        for (int nt = 0; nt < 13; ++nt)
#pragma unroll
            for (int r = 0; r < 4; ++r)
                Pw[(q * 4 + r) * 232 + nt * 16 + lr] = (__bf16)(sc[nt][r] * inv[r]);
        // zero cols 208..231 (PV k-loop reads through col 223)
        for (int idx = lane; idx < 16 * 24; idx += 64) {
            int row = idx & 15, cz = 208 + (idx >> 4);
            Pw[row * 232 + cz] = (__bf16)0.f;
        }
    }
    __syncthreads();                            // P ready (all 13 slots)

    // ---- PV over 4 dv-quarters; next quarter staged under current compute ----
    const int sbase = qt * 16 + q * 4;
    const bool sval = wactive && (sbase + 3 < 196);
    __bf16* hb = hidden + (size_t)b * 200704 + (size_t)h * 25088;

    for (int q4 = 0; q4 < 4; ++q4) {
        const __bf16* Vl = (const __bf16*)(ldsV + (q4 & 1) * 16384);
        if (q4 < 3)   // issue next quarter into the other buffer (drained by the barrier below)
            gl_lds16(gV + (size_t)(q4 + 1) * 16384 + wave * 1024 + lane * 16,
                     ldsV + ((q4 + 1) & 1) * 16384 + wave * 1024);
        if (wactive) {
            f32x4 o0 = {0.f, 0.f, 0.f, 0.f}, o1 = {0.f, 0.f, 0.f, 0.f};
#pragma unroll
            for (int kk = 0; kk < 7; ++kk) {
                bf16x8 aP = *(const bf16x8*)(Pw + lr * 232 + kk * 32 + q * 8);
                bf16x8 b0 = *(const bf16x8*)(Vl + lr * 232 + kk * 32 + q * 8);
                bf16x8 b1 = *(const bf16x8*)(Vl + (16 + lr) * 232 + kk * 32 + q * 8);
                o0 = __builtin_amdgcn_mfma_f32_16x16x32_bf16(aP, b0, o0, 0, 0, 0);
                o1 = __builtin_amdgcn_mfma_f32_16x16x32_bf16(aP, b1, o1, 0, 0, 0);
            }
            if (sval) {
#pragma unroll
                for (int nt2 = 0; nt2 < 2; ++nt2) {
                    f32x4 o = nt2 ? o1 : o0;
                    const int d = q4 * 32 + nt2 * 16 + lr;
                    bf16x4 pk;
#pragma unroll
                    for (int r = 0; r < 4; ++r) {
                        float x = o[r];
                        pk[r] = (__bf16)(x * fminf(fmaxf(x + 3.f, 0.f), 6.f) * (1.f / 6.f));
                    }
                    *(bf16x4*)(hb + (size_t)d * 196 + sbase) = pk;
                }
            }
        }
        if (q4 < 3) __syncthreads();
    }
}

} // namespace

extern "C" void kernel_launch(void* const* d_in, const int* in_sizes, int n_in,
                              void* d_out, int out_size, void* d_ws, size_t ws_size,
                              hipStream_t stream)
{
    const float* x    = (const float*)d_in[0];
    const float* Wqkv = (const float*)d_in[1];
    const float* bqkv = (const float*)d_in[2];
    const float* g1   = (const float*)d_in[3];
    const float* be1  = (const float*)d_in[4];
    const float* mu1  = (const float*)d_in[5];
    const float* va1  = (const float*)d_in[6];
    const float* Wp   = (const float*)d_in[7];
    const float* bp   = (const float*)d_in[8];
    const float* g2   = (const float*)d_in[9];
    const float* be2  = (const float*)d_in[10];
    const float* mu2  = (const float*)d_in[11];
    const float* va2  = (const float*)d_in[12];

    // workspace layout (bytes)
    char* ws = (char*)d_ws;
    __bf16* qkv    = (__bf16*)ws;                    // 25088*1536*2 = 77,070,336
    __bf16* VTp    = (__bf16*)(ws + 77070336);       // 1024*32768*2 = 67,108,864
    __bf16* hidden = (__bf16*)(ws + 144179200);      // 25088*1024*2 = 51,380,224
    __bf16* WT1    = (__bf16*)(ws + 221249536);      // 1536*512*2
    __bf16* WT2    = (__bf16*)(ws + 222822400);      // 512*1024*2
    float*  out    = (float*)d_out;

    // both weight transposes in one launch
    transpose_cvt2<<<dim3(1280), dim3(256), 0, stream>>>(Wqkv, WT1, Wp, WT2);

    // GEMM1 + BN -> qkv bf16 (Q,K) + VTp (V pre-transposed); reads f32 x directly
    gemm1_bn_scatter<<<dim3(196 * (QKVD / 128)), dim3(256), 0, stream>>>(
        x, WT1, bqkv, g1, be1, mu1, va1, qkv, VTp);

    // MFMA attention -> hidden bf16 (scrambled layout); 1 block per (b,h), 16 waves
    attn_mfma<<<dim3(Bb * Hh), dim3(1024), 0, stream>>>(qkv, VTp, hidden);

    // GEMM2 + BN -> out fp32
    gemm_bn_mfma<DIN, PIN><<<dim3(196 * (DIN / 128)), dim3(256), 0, stream>>>(
        hidden, WT2, bp, g2, be2, mu2, va2, out);
}

// Round 7
// 263.020 us; speedup vs baseline: 1.1472x; 1.1472x over previous
//
#include <hip/hip_runtime.h>
#include <math.h>

namespace {

constexpr int Bb   = 128;
constexpr int Ss   = 196;
constexpr int DIN  = 512;
constexpr int Hh   = 8;
constexpr int DKc  = 32;
constexpr int DVc  = 128;
constexpr int QKVD = 1536;   // H*(2*DK+DV)
constexpr int PIN  = 1024;   // H*DV
constexpr int Mrows = Bb * Ss; // 25088
constexpr float EPSc   = 1e-3f;
constexpr float SCALEc = 0.17677669529663687f; // 32^-0.5

typedef __bf16 bf16x8 __attribute__((ext_vector_type(8)));
typedef __bf16 bf16x4 __attribute__((ext_vector_type(4)));
typedef float  f32x4  __attribute__((ext_vector_type(4)));

// VT layout: [bh][quarter(4)][ 8192 elems ], quarter row stride 232 elems.
constexpr int VT_STRIDE = 232;                 // elems; 464 B = 16B-aligned, 2-way banks
constexpr size_t VT_QELEMS = 8192;             // padded quarter (32 rows x 232 = 7424 used)
constexpr size_t VT_BH = 4 * VT_QELEMS;        // 32768 elems per (b,h)

__device__ __forceinline__ void gl_lds16(const void* g, void* l) {
    __builtin_amdgcn_global_load_lds(
        (const __attribute__((address_space(1))) void*)g,
        (__attribute__((address_space(3))) void*)l, 16, 0, 0);
}

// ---------------- prep: both weight transposes + x f32->bf16, ONE launch ----------------
// blocks [0,768): Wqkv (K=512,N=1536); [768,1280): Wproj (K=1024,N=512);
// blocks [1280,13824): cvt x -> xb (12544 blocks x 256 thr x 1 float4 = exactly n4)
__global__ __launch_bounds__(256)
void prep(const float* __restrict__ W1, __bf16* __restrict__ WT1o,
          const float* __restrict__ W2, __bf16* __restrict__ WT2o,
          const float* __restrict__ x, __bf16* __restrict__ xb)
{
    int id = blockIdx.x;
    if (id >= 1280) {
        const int i = (id - 1280) * 256 + threadIdx.x;   // < Mrows*DIN/4 exactly
        float4 v = ((const float4*)x)[i];
        bf16x4 o = { (__bf16)v.x, (__bf16)v.y, (__bf16)v.z, (__bf16)v.w };
        ((bf16x4*)xb)[i] = o;
        return;
    }
    __shared__ float tile[32][33];
    const float* W; __bf16* WT; int K, N, bx, by;
    if (id < 768) { W = W1; WT = WT1o; K = 512;  N = 1536; bx = id % 48; by = id / 48; }
    else { id -= 768; W = W2; WT = WT2o; K = 1024; N = 512;  bx = id % 16; by = id / 16; }
    const int n0 = bx * 32, k0 = by * 32;
    const int tx = threadIdx.x & 31, ty = threadIdx.x >> 5;
#pragma unroll
    for (int i = ty; i < 32; i += 8)
        tile[i][tx] = W[(size_t)(k0 + i) * N + n0 + tx];
    __syncthreads();
#pragma unroll
    for (int i = ty; i < 32; i += 8)
        WT[(size_t)(n0 + i) * K + k0 + tx] = (__bf16)tile[tx][i];
}

// ---------------- GEMM1: xb(bf16)@Wqkv + BN, LDS-shuffle epilogue ----------------
// v5 structure (verified 63.4 us / 623 TF): double-buffered LDS K-loop, BK=64,
// global_load_lds staging (fire-and-forget DMA), ONE __syncthreads per K-step.
// Epilogue: BN + LDS overlay, QK as full 128 B lines, V as 16 B chunks into VTp.
__global__ __launch_bounds__(256)
void gemm1_bn_scatter(const __bf16* __restrict__ A, const __bf16* __restrict__ BT,
                      const float* __restrict__ bias, const float* __restrict__ gamma,
                      const float* __restrict__ beta, const float* __restrict__ mean,
                      const float* __restrict__ var,
                      __bf16* __restrict__ qkvO, __bf16* __restrict__ VTp)
{
    constexpr int N = QKVD, K = DIN;
    constexpr int BM = 128, BN = 128;
    __shared__ __align__(16) char sm[65536];

    const int t    = threadIdx.x;
    const int wave = t >> 6;
    const int lane = t & 63;
    const int lr   = lane & 15;
    const int q    = lane >> 4;

    constexpr int ntiles = N / BN;           // 12
    // T1: bijective XCD swizzle (nwg = 2352, divisible by 8).
    constexpr int nwg = 196 * ntiles;
    const int bid = (blockIdx.x & 7) * (nwg >> 3) + (blockIdx.x >> 3);
    const int m0 = (bid / ntiles) * BM;
    const int n0 = (bid % ntiles) * BN;
    const int wm = (wave & 1) * 64;
    const int wn = (wave >> 1) * 64;

    const __bf16* aG0 = A  + (size_t)(m0 + (t >> 2)) * K + (t & 3) * 8;
    const __bf16* aG1 = aG0 + (size_t)64 * K;
    const __bf16* bG0 = BT + (size_t)(n0 + (t >> 2)) * K + (t & 3) * 8;
    const __bf16* bG1 = bG0 + (size_t)64 * K;

    auto STAGE = [&](int k0, int cur) {
        char* lA = sm + cur * 16384 + wave * 1024;
        char* lB = sm + 32768 + cur * 16384 + wave * 1024;
        gl_lds16(aG0 + k0,      lA);
        gl_lds16(aG1 + k0,      lA + 4096);
        gl_lds16(aG0 + k0 + 32, lA + 8192);
        gl_lds16(aG1 + k0 + 32, lA + 8192 + 4096);
        gl_lds16(bG0 + k0,      lB);
        gl_lds16(bG1 + k0,      lB + 4096);
        gl_lds16(bG0 + k0 + 32, lB + 8192);
        gl_lds16(bG1 + k0 + 32, lB + 8192 + 4096);
    };

    f32x4 acc[4][4] = {};

    STAGE(0, 0);
    __syncthreads();                 // implicit vmcnt(0): buf0 ready
    int cur = 0;
    for (int k0 = 0; k0 < K; k0 += 64) {
        if (k0 + 64 < K) STAGE(k0 + 64, cur ^ 1);   // prefetch next tile
        const __bf16* Abuf = (const __bf16*)(sm + cur * 16384);
        const __bf16* Bbuf = (const __bf16*)(sm + 32768 + cur * 16384);
#pragma unroll
        for (int kk = 0; kk < 2; ++kk) {
            bf16x8 aF[4], bF[4];
#pragma unroll
            for (int i = 0; i < 4; ++i)
                aF[i] = *(const bf16x8*)(Abuf + kk * 4096 + (wm + i * 16 + lr) * 32 + q * 8);
#pragma unroll
            for (int j = 0; j < 4; ++j)
                bF[j] = *(const bf16x8*)(Bbuf + kk * 4096 + (wn + j * 16 + lr) * 32 + q * 8);
#pragma unroll
            for (int i = 0; i < 4; ++i)
#pragma unroll
                for (int j = 0; j < 4; ++j)
                    acc[i][j] = __builtin_amdgcn_mfma_f32_16x16x32_bf16(
                        aF[i], bF[j], acc[i][j], 0, 0, 0);
        }
        __syncthreads();             // reads of buf[cur] done + next tile landed
        cur ^= 1;
    }

    // ---- epilogue: BN + stage to LDS overlay (over the dbuf space) ----
    const int tmod = n0 % 384;
    const int cq0  = (tmod == 0) ? 0 : (tmod == 128 ? 64 : -1);
    const int vc0  = (tmod == 0) ? 64 : 0;
    const int nv   = (tmod == 256) ? 128 : 64;
    const bool qk_wave = (tmod == 0) ? (wn == 0) : (tmod == 128 ? (wn == 64) : false);

    __bf16* qkreg = (__bf16*)sm;                                   // [128][72]
    __bf16* vreg  = (__bf16*)(sm + ((nv == 128) ? 0 : 18432));     // [nv][136] col-major
    const int vbase = (nv == 128) ? wn : 0;

#pragma unroll
    for (int j = 0; j < 4; ++j) {
        const int n = n0 + wn + j * 16 + lr;
        const float s  = gamma[n] * rsqrtf(var[n] + EPSc);
        const float tv = fmaf(bias[n] - mean[n], s, beta[n]);
        if (qk_wave) {
#pragma unroll
            for (int i = 0; i < 4; ++i) {
                const int row = wm + i * 16 + q * 4;
#pragma unroll
                for (int r = 0; r < 4; ++r)
                    qkreg[(row + r) * 72 + j * 16 + lr] = (__bf16)fmaf(acc[i][j][r], s, tv);
            }
        } else {
#pragma unroll
            for (int i = 0; i < 4; ++i) {
                bf16x4 pk = { (__bf16)fmaf(acc[i][j][0], s, tv),
                              (__bf16)fmaf(acc[i][j][1], s, tv),
                              (__bf16)fmaf(acc[i][j][2], s, tv),
                              (__bf16)fmaf(acc[i][j][3], s, tv) };
                *(bf16x4*)(vreg + (vbase + j * 16 + lr) * 136 + wm + i * 16 + q * 4) = pk;
            }
        }
    }
    __syncthreads();

    // ---- QK write-out: full 128 B lines (8 lanes x 16 B) ----
    if (cq0 >= 0) {
#pragma unroll
        for (int rr = 0; rr < 4; ++rr) {
            const int row = rr * 32 + (t >> 3);
            const int l   = t & 7;
            bf16x8 vv = *(const bf16x8*)(qkreg + row * 72 + l * 8);
            *(bf16x8*)(qkvO + (size_t)(m0 + row) * N + n0 + cq0 + l * 8) = vv;
        }
    }
    // ---- V write-out: 16 B along s into VTp ----
    const int iters = (nv * 16) / 256;   // 4 or 8
    for (int it = 0; it < iters; ++it) {
        const int a  = it * 256 + t;
        const int cl = a >> 4;           // local V col
        const int r0 = (a & 15) * 8;     // tile row of first elem
        const int n  = n0 + vc0 + cl;
        const int h  = n / 192;
        const int d  = n - h * 192 - 64;
        const int mr = m0 + r0;
        const int b_ = mr / 196;
        const int s0 = mr - b_ * 196;
        __bf16* dst0 = VTp + (size_t)(b_ * 8 + h) * VT_BH
                     + (size_t)(d >> 5) * VT_QELEMS + (size_t)(d & 31) * VT_STRIDE;
        bf16x8 vv = *(const bf16x8*)(vreg + cl * 136 + r0);
        if (s0 <= 188) {
            *(bf16x8*)(dst0 + s0) = vv;
        } else {
            // chunk straddles a batch boundary (s wraps at 196): scalar split
#pragma unroll
            for (int e = 0; e < 8; ++e) {
                int se = s0 + e;
                __bf16* dst = dst0;
                if (se >= 196) { se -= 196; dst += 8 * VT_BH; }
                dst[se] = vv[e];
            }
        }
    }
}

// ---------------- generic bf16 MFMA GEMM + BN (fp32 out) — GEMM2 ----------------
// v5 structure: double-buffered single-barrier K-loop.
template<int N, int K>
__global__ __launch_bounds__(256)
void gemm_bn_mfma(const __bf16* __restrict__ A, const __bf16* __restrict__ BT,
                  const float* __restrict__ bias, const float* __restrict__ gamma,
                  const float* __restrict__ beta, const float* __restrict__ mean,
                  const float* __restrict__ var, float* __restrict__ C)
{
    constexpr int BM = 128, BN = 128;
    __shared__ __align__(16) char sm[65536];
    const int t    = threadIdx.x;
    const int wave = t >> 6;
    const int lane = t & 63;
    const int lr   = lane & 15;
    const int q    = lane >> 4;
    constexpr int ntiles = N / BN;
    constexpr int nwg = 196 * ntiles;        // 784 for N=512 -> divisible by 8
    const int bid = (blockIdx.x & 7) * (nwg >> 3) + (blockIdx.x >> 3);
    const int m0 = (bid / ntiles) * BM;
    const int n0 = (bid % ntiles) * BN;
    const int wm = (wave & 1) * 64;
    const int wn = (wave >> 1) * 64;
    const __bf16* aG0 = A  + (size_t)(m0 + (t >> 2)) * K + (t & 3) * 8;
    const __bf16* aG1 = aG0 + (size_t)64 * K;
    const __bf16* bG0 = BT + (size_t)(n0 + (t >> 2)) * K + (t & 3) * 8;
    const __bf16* bG1 = bG0 + (size_t)64 * K;

    auto STAGE = [&](int k0, int cur) {
        char* lA = sm + cur * 16384 + wave * 1024;
        char* lB = sm + 32768 + cur * 16384 + wave * 1024;
        gl_lds16(aG0 + k0,      lA);
        gl_lds16(aG1 + k0,      lA + 4096);
        gl_lds16(aG0 + k0 + 32, lA + 8192);
        gl_lds16(aG1 + k0 + 32, lA + 8192 + 4096);
        gl_lds16(bG0 + k0,      lB);
        gl_lds16(bG1 + k0,      lB + 4096);
        gl_lds16(bG0 + k0 + 32, lB + 8192);
        gl_lds16(bG1 + k0 + 32, lB + 8192 + 4096);
    };

    f32x4 acc[4][4] = {};

    STAGE(0, 0);
    __syncthreads();
    int cur = 0;
    for (int k0 = 0; k0 < K; k0 += 64) {
        if (k0 + 64 < K) STAGE(k0 + 64, cur ^ 1);
        const __bf16* Abuf = (const __bf16*)(sm + cur * 16384);
        const __bf16* Bbuf = (const __bf16*)(sm + 32768 + cur * 16384);
#pragma unroll
        for (int kk = 0; kk < 2; ++kk) {
            bf16x8 aF[4], bF[4];
#pragma unroll
            for (int i = 0; i < 4; ++i)
                aF[i] = *(const bf16x8*)(Abuf + kk * 4096 + (wm + i * 16 + lr) * 32 + q * 8);
#pragma unroll
            for (int j = 0; j < 4; ++j)
                bF[j] = *(const bf16x8*)(Bbuf + kk * 4096 + (wn + j * 16 + lr) * 32 + q * 8);
#pragma unroll
            for (int i = 0; i < 4; ++i)
#pragma unroll
                for (int j = 0; j < 4; ++j)
                    acc[i][j] = __builtin_amdgcn_mfma_f32_16x16x32_bf16(
                        aF[i], bF[j], acc[i][j], 0, 0, 0);
        }
        __syncthreads();
        cur ^= 1;
    }
#pragma unroll
    for (int j = 0; j < 4; ++j) {
        const int n = n0 + wn + j * 16 + lr;
        const float s  = gamma[n] * rsqrtf(var[n] + EPSc);
        const float tv = fmaf(bias[n] - mean[n], s, beta[n]);
#pragma unroll
        for (int i = 0; i < 4; ++i) {
            const int mrow = m0 + wm + i * 16 + q * 4;
#pragma unroll
            for (int r = 0; r < 4; ++r)
                C[(size_t)(mrow + r) * N + n] = fmaf(acc[i][j][r], s, tv);
        }
    }
}

// ---------------- MFMA attention: one block per (b,h), 16 waves ----------------
// v7: pre-PV barrier REMOVED — each P slot is written and read only by its
// owning wave (in-wave lgkmcnt ordering suffices); V-buffer discipline is
// enforced by the first barrier (V0 landed) and the per-q4 end barriers
// (each wave's own gl_lds drains at its barrier entry). Early waves destagger
// into PV staging.
__global__ __launch_bounds__(1024)
void attn_mfma(const __bf16* __restrict__ qkv, const __bf16* __restrict__ VTp,
               __bf16* __restrict__ hidden)
{
    __shared__ __align__(16) char smem[145920];
    __bf16* Kb = (__bf16*)smem;

    const int t = threadIdx.x;
    const int wave = t >> 6, lane = t & 63;
    const int lr = lane & 15, q = lane >> 4;
    const int bh = blockIdx.x;
    const int b = bh >> 3, h = bh & 7;
    const __bf16* qkvb = qkv + (size_t)b * 196 * QKVD + h * 192;

    // ---- issue V quarter 0 stage FIRST so HBM latency drains under K staging ----
    const char* gV = (const char*)(VTp + (size_t)bh * VT_BH);
    char* ldsV = smem + 113152;                 // 2 x 16384 double buffer
    gl_lds16(gV + wave * 1024 + lane * 16, ldsV + wave * 1024);

    // ---- stage K once: rows s=0..195, ch 32..63 -> Kb[s][40] ----
    if (t < 196 * 4) {
        const int s = t >> 2, c = t & 3;
        bf16x8 v = *(const bf16x8*)(qkvb + (size_t)s * QKVD + 32 + c * 8);
        *(bf16x8*)(Kb + s * 40 + c * 8) = v;
    }

    __syncthreads();                            // K ready; barrier drains vmcnt -> V0 ready

    const int qt = wave;                        // q-tile; valid rows only for qt<=12
    const bool wactive = (qt <= 12);
    __bf16* Pw = (__bf16*)(smem + 16640 + (wactive ? qt : 0) * 7424);   // [16][232]

    if (wactive) {
        // Q fragment straight from global
        int sQ = qt * 16 + lr; if (sQ > 195) sQ = 195;
        bf16x8 aQ = *(const bf16x8*)(qkv + ((size_t)b * 196 + sQ) * QKVD + h * 192 + q * 8);

        f32x4 sc[13];
#pragma unroll
        for (int nt = 0; nt < 13; ++nt) {
            bf16x8 bK = *(const bf16x8*)(Kb + (nt * 16 + lr) * 40 + q * 8);
            f32x4 z = {0.f, 0.f, 0.f, 0.f};
            sc[nt] = __builtin_amdgcn_mfma_f32_16x16x32_bf16(aQ, bK, z, 0, 0, 0);
        }
        // ---- register softmax over the 208 cols (cols>=196 masked) ----
        float mrow[4] = {-1e30f, -1e30f, -1e30f, -1e30f};
#pragma unroll
        for (int nt = 0; nt < 13; ++nt) {
            const bool valid = (nt < 12) | (lr < 4);
#pragma unroll
            for (int r = 0; r < 4; ++r) {
                float x = sc[nt][r] * SCALEc;
                sc[nt][r] = x;
                if (valid) mrow[r] = fmaxf(mrow[r], x);
            }
        }
#pragma unroll
        for (int d = 1; d < 16; d <<= 1)
#pragma unroll
            for (int r = 0; r < 4; ++r)
                mrow[r] = fmaxf(mrow[r], __shfl_xor(mrow[r], d, 64));
        float l[4] = {0.f, 0.f, 0.f, 0.f};
#pragma unroll
        for (int nt = 0; nt < 13; ++nt) {
            const bool valid = (nt < 12) | (lr < 4);
#pragma unroll
            for (int r = 0; r < 4; ++r) {
                float e = valid ? __expf(sc[nt][r] - mrow[r]) : 0.f;
                sc[nt][r] = e;
                l[r] += e;
            }
        }
#pragma unroll
        for (int d = 1; d < 16; d <<= 1)
#pragma unroll
            for (int r = 0; r < 4; ++r)
                l[r] += __shfl_xor(l[r], d, 64);
        float inv[4];
#pragma unroll
        for (int r = 0; r < 4; ++r) inv[r] = 1.f / l[r];

        // ---- P to LDS in A-operand layout: P[m=quad*4+r][col] (wave-private slot) ----
#pragma unroll
        for (int nt = 0; nt < 13; ++nt)
#pragma unroll
            for (int r = 0; r < 4; ++r)
                Pw[(q * 4 + r) * 232 + nt * 16 + lr] = (__bf16)(sc[nt][r] * inv[r]);
        // zero cols 208..231 (PV k-loop reads through col 223)
        for (int idx = lane; idx < 16 * 24; idx += 64) {
            int row = idx & 15, cz = 208 + (idx >> 4);
            Pw[row * 232 + cz] = (__bf16)0.f;
        }
    }
    // NOTE: no barrier here — P slots are wave-private (write->read ordered by lgkmcnt).

    // ---- PV over 4 dv-quarters; next quarter staged under current compute ----
    const int sbase = qt * 16 + q * 4;
    const bool sval = wactive && (sbase + 3 < 196);
    __bf16* hb = hidden + (size_t)b * 200704 + (size_t)h * 25088;

    for (int q4 = 0; q4 < 4; ++q4) {
        const __bf16* Vl = (const __bf16*)(ldsV + (q4 & 1) * 16384);
        if (q4 < 3)   // issue next quarter into the other buffer (drained by the barrier below)
            gl_lds16(gV + (size_t)(q4 + 1) * 16384 + wave * 1024 + lane * 16,
                     ldsV + ((q4 + 1) & 1) * 16384 + wave * 1024);
        if (wactive) {
            f32x4 o0 = {0.f, 0.f, 0.f, 0.f}, o1 = {0.f, 0.f, 0.f, 0.f};
#pragma unroll
            for (int kk = 0; kk < 7; ++kk) {
                bf16x8 aP = *(const bf16x8*)(Pw + lr * 232 + kk * 32 + q * 8);
                bf16x8 b0 = *(const bf16x8*)(Vl + lr * 232 + kk * 32 + q * 8);
                bf16x8 b1 = *(const bf16x8*)(Vl + (16 + lr) * 232 + kk * 32 + q * 8);
                o0 = __builtin_amdgcn_mfma_f32_16x16x32_bf16(aP, b0, o0, 0, 0, 0);
                o1 = __builtin_amdgcn_mfma_f32_16x16x32_bf16(aP, b1, o1, 0, 0, 0);
            }
            if (sval) {
#pragma unroll
                for (int nt2 = 0; nt2 < 2; ++nt2) {
                    f32x4 o = nt2 ? o1 : o0;
                    const int d = q4 * 32 + nt2 * 16 + lr;
                    bf16x4 pk;
#pragma unroll
                    for (int r = 0; r < 4; ++r) {
                        float x = o[r];
                        pk[r] = (__bf16)(x * fminf(fmaxf(x + 3.f, 0.f), 6.f) * (1.f / 6.f));
                    }
                    *(bf16x4*)(hb + (size_t)d * 196 + sbase) = pk;
                }
            }
        }
        if (q4 < 3) __syncthreads();
    }
}

} // namespace

extern "C" void kernel_launch(void* const* d_in, const int* in_sizes, int n_in,
                              void* d_out, int out_size, void* d_ws, size_t ws_size,
                              hipStream_t stream)
{
    const float* x    = (const float*)d_in[0];
    const float* Wqkv = (const float*)d_in[1];
    const float* bqkv = (const float*)d_in[2];
    const float* g1   = (const float*)d_in[3];
    const float* be1  = (const float*)d_in[4];
    const float* mu1  = (const float*)d_in[5];
    const float* va1  = (const float*)d_in[6];
    const float* Wp   = (const float*)d_in[7];
    const float* bp   = (const float*)d_in[8];
    const float* g2   = (const float*)d_in[9];
    const float* be2  = (const float*)d_in[10];
    const float* mu2  = (const float*)d_in[11];
    const float* va2  = (const float*)d_in[12];

    // workspace layout (bytes)
    char* ws = (char*)d_ws;
    __bf16* qkv    = (__bf16*)ws;                    // 25088*1536*2 = 77,070,336
    __bf16* VTp    = (__bf16*)(ws + 77070336);       // 1024*32768*2 = 67,108,864
    __bf16* hidden = (__bf16*)(ws + 144179200);      // 25088*1024*2 = 51,380,224
    __bf16* xb     = (__bf16*)(ws + 195559424);      // 25088*512*2  = 25,690,112
    __bf16* WT1    = (__bf16*)(ws + 221249536);      // 1536*512*2
    __bf16* WT2    = (__bf16*)(ws + 222822400);      // 512*1024*2
    float*  out    = (float*)d_out;

    // weight transposes + x cvt in one launch
    prep<<<dim3(13824), dim3(256), 0, stream>>>(Wqkv, WT1, Wp, WT2, x, xb);

    // GEMM1 + BN -> qkv bf16 (Q,K) + VTp (V pre-transposed)
    gemm1_bn_scatter<<<dim3(196 * (QKVD / 128)), dim3(256), 0, stream>>>(
        xb, WT1, bqkv, g1, be1, mu1, va1, qkv, VTp);

    // MFMA attention -> hidden bf16 (scrambled layout); 1 block per (b,h), 16 waves
    attn_mfma<<<dim3(Bb * Hh), dim3(1024), 0, stream>>>(qkv, VTp, hidden);

    // GEMM2 + BN -> out fp32
    gemm_bn_mfma<DIN, PIN><<<dim3(196 * (DIN / 128)), dim3(256), 0, stream>>>(
        hidden, WT2, bp, g2, be2, mu2, va2, out);
}